// Round 4
// baseline (1519.101 us; speedup 1.0000x reference)
//
#include <hip/hip_runtime.h>

// ---------------- problem constants ----------------
#define NWIN   960
#define PP     144          // patches per window
#define CC     192          // dim
#define HH     6            // heads
#define DD     32           // head dim
#define TT     64           // type_of_windows
#define PQ     (PP*PP)      // 20736
#define MROWS  (NWIN*PP)    // 138240
#define NQKV   576
#define KT     48           // k-tile size in attention
#define QSCALE 0.17677669529663687f   // 32^-0.5

// Workspace budget: d_ws holds ONLY the attention output AO
//   (26,542,080 floats = exactly out_size bytes).
// Expanded bias lives in the first 7,962,624 floats of d_out (k3 overwrites
// d_out last, so this is safe under stream ordering and is rebuilt every call).

// ---------------- K0: bias expansion ----------------
// bias_ws[th][pq] = bias_table[pidx[pq]*384 + th]   (th = t*6+h, 384 total)
__global__ __launch_bounds__(256) void k0_bias_expand(
    const float* __restrict__ table, const int* __restrict__ pidx,
    float* __restrict__ bias_ws)
{
    int pq = blockIdx.x * 256 + threadIdx.x;   // 81*256 == 20736 exactly
    int idx = pidx[pq];
    const float* row = table + (long)idx * 384;
    for (int th = 0; th < 384; ++th) {
        bias_ws[(unsigned)th * PQ + pq] = row[th];
    }
}

// ---------------- K2: fused QKV projection + attention ----------------
// One block per (window, head). Computes Q (144x32, once) and K/V tiles
// (48x64 per k-tile) from x @ Wqkv slices, then online-softmax attention.
__global__ __launch_bounds__(256) void k2_fused(
    const float* __restrict__ x, const float* __restrict__ Wqkv,
    const float* __restrict__ bqkv, const float* __restrict__ mask,
    const float* __restrict__ bias_ws, float* __restrict__ ao)
{
    __shared__ float Qs[DD][PP + 1];   // Q d-major, 4640 fl
    __shared__ float Ks[DD][KT + 1];   // K tile d-major, 1568 fl
    __shared__ float Vs[KT][DD];       // V tile row-major, 1536 fl
    __shared__ float UN[6912];         // union: Ps[144][48] / staging buffers
    // lifetimes: staging (pre-GEMM) and Ps (softmax->PV) never overlap

    const int tid = threadIdx.x;
    const int wh = blockIdx.x;
    const int w = wh / HH;
    const int h = wh % HH;
    const int th = (w % TT) * HH + h;
    const float* xw = x + (long)w * PP * CC;
    const float* mb = mask + (long)w * PQ;
    const float* bb = bias_ws + (long)th * PQ;

    const int tp = tid >> 4;       // 0..15: owns 9 q-rows
    const int tq = tid & 15;       // 0..15
    const int p0 = tp * 9;
    const int q0 = tq * 3;         // 3 score-cols per tile
    const int d0 = tq * 2;         // 2 output dims

    // ======== Phase 0: Q = (x_w @ Wq_h + bq) * scale  -> Qs (d-major) ====
    {
        float qacc[9][2];
#pragma unroll
        for (int i = 0; i < 9; ++i) { qacc[i][0] = 0.f; qacc[i][1] = 0.f; }

        for (int kc = 0; kc < CC; kc += 32) {
            float* Xs = UN;                 // [144][33] scalar-accessed
            float* Wq = UN + 4752;          // [32][33]  scalar-accessed
            __syncthreads();                // protect UN restage
            for (int idx = tid; idx < 1152; idx += 256) {   // 144 rows x 8 f4
                int p = idx >> 3;
                int cq = (idx & 7) * 4;
                float4 g = *(const float4*)&xw[(long)p * CC + kc + cq];
                Xs[p * 33 + cq + 0] = g.x; Xs[p * 33 + cq + 1] = g.y;
                Xs[p * 33 + cq + 2] = g.z; Xs[p * 33 + cq + 3] = g.w;
            }
            {   // 32 rows x 8 float4 = 256 items, one per thread
                int r = tid >> 3;
                int cq = (tid & 7) * 4;
                float4 g = *(const float4*)&Wqkv[(long)(kc + r) * NQKV + h * DD + cq];
                Wq[r * 33 + cq + 0] = g.x; Wq[r * 33 + cq + 1] = g.y;
                Wq[r * 33 + cq + 2] = g.z; Wq[r * 33 + cq + 3] = g.w;
            }
            __syncthreads();
            for (int c = 0; c < 32; ++c) {
                float b0 = Wq[c * 33 + d0];
                float b1 = Wq[c * 33 + d0 + 1];
                float a[9];
#pragma unroll
                for (int i = 0; i < 9; ++i) a[i] = Xs[(p0 + i) * 33 + c];
#pragma unroll
                for (int i = 0; i < 9; ++i) {
                    qacc[i][0] = fmaf(a[i], b0, qacc[i][0]);
                    qacc[i][1] = fmaf(a[i], b1, qacc[i][1]);
                }
            }
        }
        float bq0 = bqkv[h * DD + d0], bq1 = bqkv[h * DD + d0 + 1];
#pragma unroll
        for (int i = 0; i < 9; ++i) {
            Qs[d0 + 0][p0 + i] = (qacc[i][0] + bq0) * QSCALE;
            Qs[d0 + 1][p0 + i] = (qacc[i][1] + bq1) * QSCALE;
        }
        // visibility of Qs guaranteed by barriers inside the tile loop below
    }

    float O[9][2];
    float mrun[9], lrun[9];
#pragma unroll
    for (int i = 0; i < 9; ++i) {
        O[i][0] = 0.f; O[i][1] = 0.f;
        mrun[i] = -INFINITY; lrun[i] = 0.f;
    }

    const int ty = tid >> 4;       // rows of K/V tile: 3 each
    const int tx = tid & 15;       // cols of [48][64] tile: 4 each

    // ======== k-tiles ========
    for (int kt = 0; kt < 3; ++kt) {
        const int qoff = kt * KT;

        // ---- K/V tile projection: [48 rows][64 cols = K(32)|V(32)] ----
        float kv[3][4];
#pragma unroll
        for (int i = 0; i < 3; ++i)
#pragma unroll
            for (int j = 0; j < 4; ++j) kv[i][j] = 0.f;

        for (int kc = 0; kc < CC; kc += 32) {
            float* Xs2 = UN;               // [48][33] scalar-accessed
            float* Wkv = UN + 1584;        // [32][64] — stride 64: float4-aligned
            __syncthreads();               // protect UN restage (also fences
                                           // prev tile's PV reads of Ps/Vs)
            for (int idx = tid; idx < 384; idx += 256) {    // 48 rows x 8 f4
                int r = idx >> 3;
                int cq = (idx & 7) * 4;
                float4 g = *(const float4*)&xw[(long)(qoff + r) * CC + kc + cq];
                Xs2[r * 33 + cq + 0] = g.x; Xs2[r * 33 + cq + 1] = g.y;
                Xs2[r * 33 + cq + 2] = g.z; Xs2[r * 33 + cq + 3] = g.w;
            }
            for (int idx = tid; idx < 512; idx += 256) {    // 32 rows x 16 f4
                int r = idx >> 4;
                int q8 = idx & 15;
                int col  = (q8 < 8) ? (192 + h * DD + q8 * 4)
                                    : (384 + h * DD + (q8 - 8) * 4);
                int lcol = q8 * 4;          // 0..31 = K, 32..63 = V
                float4 g = *(const float4*)&Wqkv[(long)(kc + r) * NQKV + col];
                *(float4*)&Wkv[r * 64 + lcol] = g;
            }
            __syncthreads();
            for (int c = 0; c < 32; ++c) {
                float a2[3];
#pragma unroll
                for (int i = 0; i < 3; ++i) a2[i] = Xs2[(ty * 3 + i) * 33 + c];
                float4 b4 = *(float4*)&Wkv[c * 64 + tx * 4];   // 16B-aligned
#pragma unroll
                for (int i = 0; i < 3; ++i) {
                    kv[i][0] = fmaf(a2[i], b4.x, kv[i][0]);
                    kv[i][1] = fmaf(a2[i], b4.y, kv[i][1]);
                    kv[i][2] = fmaf(a2[i], b4.z, kv[i][2]);
                    kv[i][3] = fmaf(a2[i], b4.w, kv[i][3]);
                }
            }
        }
        __syncthreads();   // micro-GEMM reads done; prior S/PV reads of Ks/Vs long done

        // write K (d-major) / V (row-major) with bias
        if (tx < 8) {
            int dc = tx * 4;
            float4 bk = *(const float4*)&bqkv[192 + h * DD + dc];
#pragma unroll
            for (int i = 0; i < 3; ++i) {
                int r = ty * 3 + i;
                Ks[dc + 0][r] = kv[i][0] + bk.x;
                Ks[dc + 1][r] = kv[i][1] + bk.y;
                Ks[dc + 2][r] = kv[i][2] + bk.z;
                Ks[dc + 3][r] = kv[i][3] + bk.w;
            }
        } else {
            int dc = tx * 4 - 32;
            float4 bv = *(const float4*)&bqkv[384 + h * DD + dc];
#pragma unroll
            for (int i = 0; i < 3; ++i) {
                int r = ty * 3 + i;
                float4 o;
                o.x = kv[i][0] + bv.x; o.y = kv[i][1] + bv.y;
                o.z = kv[i][2] + bv.z; o.w = kv[i][3] + bv.w;
                *(float4*)&Vs[r][dc] = o;
            }
        }
        __syncthreads();

        // ---- S tile: 9x3 micro-GEMM over d=32 ----
        float acc[9][3];
#pragma unroll
        for (int i = 0; i < 9; ++i)
#pragma unroll
            for (int j = 0; j < 3; ++j) acc[i][j] = 0.f;

        for (int d = 0; d < DD; ++d) {
            float a[9], b[3];
#pragma unroll
            for (int i = 0; i < 9; ++i) a[i] = Qs[d][p0 + i];
#pragma unroll
            for (int j = 0; j < 3; ++j) b[j] = Ks[d][q0 + j];
#pragma unroll
            for (int i = 0; i < 9; ++i)
#pragma unroll
                for (int j = 0; j < 3; ++j) acc[i][j] = fmaf(a[i], b[j], acc[i][j]);
        }

        // ---- bias + mask + online softmax; Ps lives in UN ----
        float* Ps = UN;   // [144][48]
        float tmax[9];
#pragma unroll
        for (int i = 0; i < 9; ++i) {
            tmax[i] = -INFINITY;
            int pp = p0 + i;
#pragma unroll
            for (int j = 0; j < 3; ++j) {
                int qq = qoff + q0 + j;
                float s = acc[i][j] + bb[pp * PP + qq] + mb[pp * PP + qq];
                acc[i][j] = s;
                tmax[i] = fmaxf(tmax[i], s);
            }
        }
#pragma unroll
        for (int i = 0; i < 9; ++i) {
#pragma unroll
            for (int off = 1; off < 16; off <<= 1)
                tmax[i] = fmaxf(tmax[i], __shfl_xor(tmax[i], off, 16));
        }
#pragma unroll
        for (int i = 0; i < 9; ++i) {
            float mnew = fmaxf(mrun[i], tmax[i]);
            float scal = __expf(mrun[i] - mnew);   // first tile: exp(-inf)=0
            float psum = 0.f;
#pragma unroll
            for (int j = 0; j < 3; ++j) {
                float p = __expf(acc[i][j] - mnew);
                Ps[(p0 + i) * KT + q0 + j] = p;
                psum += p;
            }
#pragma unroll
            for (int off = 1; off < 16; off <<= 1)
                psum += __shfl_xor(psum, off, 16);
            lrun[i] = lrun[i] * scal + psum;
            O[i][0] *= scal; O[i][1] *= scal;
            mrun[i] = mnew;
        }
        __syncthreads();

        // ---- PV: O[9][2] += Ps[144][48] @ Vs[48][32] ----
        for (int qq = 0; qq < KT; ++qq) {
            float2 v2 = *(const float2*)&Vs[qq][d0];
#pragma unroll
            for (int i = 0; i < 9; ++i) {
                float p = Ps[(p0 + i) * KT + qq];
                O[i][0] = fmaf(p, v2.x, O[i][0]);
                O[i][1] = fmaf(p, v2.y, O[i][1]);
            }
        }
        // next iteration's first __syncthreads() fences Ps/Vs reuse
    }

    // finalize: ao[(w*144+p)*192 + h*32 + d]
#pragma unroll
    for (int i = 0; i < 9; ++i) {
        float inv = 1.f / lrun[i];
        float2 o2; o2.x = O[i][0] * inv; o2.y = O[i][1] * inv;
        *(float2*)&ao[((long)(w * PP + p0 + i)) * CC + h * DD + d0] = o2;
    }
}

// ---------------- K3: output projection GEMM ----------------
#define BM 128
#define BN 64
#define KC 64
__global__ __launch_bounds__(256) void k3_proj(
    const float* __restrict__ ain, const float* __restrict__ Wout,
    const float* __restrict__ bout, float* __restrict__ out)
{
    __shared__ float As[BM][KC + 1];
    __shared__ float Bs[KC][BN];

    const int tid = threadIdx.x;
    const int rowBase = blockIdx.x * BM;
    const int colBase = blockIdx.y * BN;
    const int r0 = (tid >> 4) * 8;
    const int c0 = (tid & 15) * 4;

    float acc[8][4];
#pragma unroll
    for (int i = 0; i < 8; ++i)
#pragma unroll
        for (int j = 0; j < 4; ++j) acc[i][j] = 0.f;

    for (int kc = 0; kc < CC; kc += KC) {
#pragma unroll
        for (int it = 0; it < 8; ++it) {
            int idx = tid + it * 256;
            int row = idx >> 4;
            int kq  = (idx & 15) * 4;
            float4 g = *(const float4*)&ain[(long)(rowBase + row) * CC + kc + kq];
            As[row][kq + 0] = g.x; As[row][kq + 1] = g.y;
            As[row][kq + 2] = g.z; As[row][kq + 3] = g.w;
        }
#pragma unroll
        for (int it = 0; it < 4; ++it) {
            int idx = tid + it * 256;
            int kk = idx >> 4;
            int n0 = (idx & 15) * 4;
            float4 g = *(const float4*)&Wout[(long)(kc + kk) * CC + colBase + n0];
            *(float4*)&Bs[kk][n0] = g;
        }
        __syncthreads();

        for (int kk = 0; kk < KC; ++kk) {
            float4 b4 = *(const float4*)&Bs[kk][c0];
            float a[8];
#pragma unroll
            for (int i = 0; i < 8; ++i) a[i] = As[r0 + i][kk];
#pragma unroll
            for (int i = 0; i < 8; ++i) {
                acc[i][0] = fmaf(a[i], b4.x, acc[i][0]);
                acc[i][1] = fmaf(a[i], b4.y, acc[i][1]);
                acc[i][2] = fmaf(a[i], b4.z, acc[i][2]);
                acc[i][3] = fmaf(a[i], b4.w, acc[i][3]);
            }
        }
        __syncthreads();
    }

    const int c = colBase + c0;
    float b0 = bout[c], b1 = bout[c + 1], b2 = bout[c + 2], b3 = bout[c + 3];
#pragma unroll
    for (int i = 0; i < 8; ++i) {
        int m = rowBase + r0 + i;
        float4 o;
        o.x = acc[i][0] + b0; o.y = acc[i][1] + b1;
        o.z = acc[i][2] + b2; o.w = acc[i][3] + b3;
        *(float4*)&out[(long)m * CC + c] = o;
    }
}

// ---------------- launch ----------------
extern "C" void kernel_launch(void* const* d_in, const int* in_sizes, int n_in,
                              void* d_out, int out_size, void* d_ws, size_t ws_size,
                              hipStream_t stream) {
    const float* x     = (const float*)d_in[0];
    const float* mask  = (const float*)d_in[1];
    const float* Wqkv  = (const float*)d_in[2];
    const float* bqkv  = (const float*)d_in[3];
    const float* Wout  = (const float*)d_in[4];
    const float* bout  = (const float*)d_in[5];
    const float* btab  = (const float*)d_in[6];
    const int*   pidx  = (const int*)d_in[7];
    float* out = (float*)d_out;
    float* ws  = (float*)d_ws;

    float* bws = out;   // expanded bias: first 7,962,624 floats of d_out
    float* ao  = ws;    // attention output: 26,542,080 floats (== out_size bytes)

    hipLaunchKernelGGL(k0_bias_expand, dim3(81), dim3(256), 0, stream,
                       btab, pidx, bws);
    hipLaunchKernelGGL(k2_fused, dim3(NWIN * HH), dim3(256), 0, stream,
                       x, Wqkv, bqkv, mask, bws, ao);
    hipLaunchKernelGGL(k3_proj, dim3(MROWS / BM, CC / BN), dim3(256), 0, stream,
                       ao, Wout, bout, out);
}